// Round 7
// baseline (436.644 us; speedup 1.0000x reference)
//
#include <hip/hip_runtime.h>
#include <hip/hip_bf16.h>
#include <stdint.h>

#define BB 4
#define SS 2048
#define HH 1024
#define NHH 16
#define HDD 64
#define M_TOT (BB*SS)          // 8192

// workspace layout (ushort/bf16 element offsets)
#define XB_OFF 0                              // hidden bf16 [8192][1024]
#define WT_OFF (M_TOT*HH)                     // Wq^T,Wk^T,Wv^T bf16 [3][N=1024][K=1024]
#define Q_OFF  (WT_OFF + 3*HH*HH)             // Q  [B][NH][S][HD]  (pre-scaled by 0.125*log2e!)
#define K_OFF  (Q_OFF + BB*NHH*SS*HDD)        // K  [B][NH][S][HD]
#define VT_OFF (K_OFF + BB*NHH*SS*HDD)        // Vt [B][NH][HD][S]  (transposed)

typedef short bf16x8 __attribute__((ext_vector_type(8)));
typedef float f32x4  __attribute__((ext_vector_type(4)));

__device__ inline unsigned short f2bf(float f){
  unsigned u = __float_as_uint(f);
  u += 0x7fffu + ((u >> 16) & 1u);   // RNE
  return (unsigned short)(u >> 16);
}
__device__ inline unsigned pk2bf(float lo, float hi){
  float2 t; t.x = lo; t.y = hi;
  __hip_bfloat162 h = __float22bfloat162_rn(t);
  return *(unsigned*)&h;
}

// async global->LDS, 16B per lane
__device__ __forceinline__ void ld_g2l_16(const unsigned short* g, unsigned short* l){
  __builtin_amdgcn_global_load_lds(
      (const __attribute__((address_space(1))) void*)g,
      (__attribute__((address_space(3))) void*)l, 16, 0, 0);
}

// ---------------- kernel 1a: X fp32 -> bf16 ----------------
__global__ void convert_x(const float* __restrict__ hs, unsigned short* __restrict__ xb){
  const int i = blockIdx.x*blockDim.x + threadIdx.x;
  float4 v = ((const float4*)hs)[i];
  ushort4 o;
  o.x = f2bf(v.x); o.y = f2bf(v.y); o.z = f2bf(v.z); o.w = f2bf(v.w);
  ((ushort4*)xb)[i] = o;
}

// ---------------- kernel 1b: W [K][N] fp32 -> WT [N][K] bf16 ----------------
__global__ void convert_wt(const float* __restrict__ wq, const float* __restrict__ wk,
                           const float* __restrict__ wv, unsigned short* __restrict__ wt){
  __shared__ unsigned short t[64][65];
  const int z = blockIdx.z;
  const float* W = (z==0) ? wq : ((z==1) ? wk : wv);
  unsigned short* WT = wt + z*HH*HH;
  const int kb = blockIdx.x*64, nb = blockIdx.y*64;
  const int tid = threadIdx.x;
  #pragma unroll
  for (int i = 0; i < 16; i++){
    const int idx = i*256 + tid;
    const int r = idx >> 6, c = idx & 63;
    t[r][c] = f2bf(W[(kb + r)*HH + nb + c]);
  }
  __syncthreads();
  #pragma unroll
  for (int i = 0; i < 16; i++){
    const int idx = i*256 + tid;
    const int n = idx >> 6, k = idx & 63;
    WT[(nb + n)*HH + kb + k] = t[k][n];
  }
}

// ---------------- kernel 2: QKV projection GEMM (m97 structure) ----------------
// z==0 (Q) output is pre-scaled by 0.125*log2e so attention needs no per-score fma.
__global__ __launch_bounds__(256) void qkv_gemm(
    const unsigned short* __restrict__ ws16, unsigned short* __restrict__ wsq,
    const float* __restrict__ bq, const float* __restrict__ bk, const float* __restrict__ bv,
    const float* __restrict__ qe, const float* __restrict__ ke, const float* __restrict__ ve,
    const int* __restrict__ idxp){
  __shared__ unsigned short al[128*32];
  __shared__ unsigned short bl[128*32];

  const unsigned short* Xb = ws16 + XB_OFF;
  const int z = blockIdx.z;
  const unsigned short* Wt = ws16 + WT_OFF + z*HH*HH;
  const float* bias = (z==0) ? bq : ((z==1) ? bk : bv);
  const float* emb  = (z==0) ? qe : ((z==1) ? ke : ve);

  const int tid  = threadIdx.x;
  const int wv   = tid >> 6;
  const int ln   = tid & 63;
  const int quad = ln >> 4;
  const int l15  = ln & 15;
  const int m0 = blockIdx.x * 128;
  const int n0 = blockIdx.y * 128;
  const int wm = wv & 1, wn = wv >> 1;

  const int sr0 = wv*32 + (ln >> 2);
  const int sr1 = sr0 + 16;
  const int sk  = (ln & 3)*8;
  const unsigned short* ga0 = &Xb[(size_t)(m0 + sr0)*HH + sk];
  const unsigned short* ga1 = &Xb[(size_t)(m0 + sr1)*HH + sk];
  const unsigned short* gb0 = &Wt[(size_t)(n0 + sr0)*HH + sk];
  const unsigned short* gb1 = &Wt[(size_t)(n0 + sr1)*HH + sk];
  unsigned short* alb0 = &al[wv*1024];
  unsigned short* alb1 = &al[wv*1024 + 512];
  unsigned short* blb0 = &bl[wv*1024];
  unsigned short* blb1 = &bl[wv*1024 + 512];

  f32x4 acc[4][4] = {};

  for (int k0 = 0; k0 < HH; k0 += 32){
    __syncthreads();
    ld_g2l_16(ga0 + k0, alb0);
    ld_g2l_16(ga1 + k0, alb1);
    ld_g2l_16(gb0 + k0, blb0);
    ld_g2l_16(gb1 + k0, blb1);
    __syncthreads();

    bf16x8 af[4], bf[4];
    #pragma unroll
    for (int i = 0; i < 4; i++){
      af[i] = *(const bf16x8*)&al[(wm*64 + i*16 + l15)*32 + quad*8];
      bf[i] = *(const bf16x8*)&bl[(wn*64 + i*16 + l15)*32 + quad*8];
    }
    #pragma unroll
    for (int mi = 0; mi < 4; mi++)
      #pragma unroll
      for (int ni = 0; ni < 4; ni++)
        acc[mi][ni] = __builtin_amdgcn_mfma_f32_16x16x32_bf16(af[mi], bf[ni], acc[mi][ni], 0, 0, 0);
  }

  const int index = idxp[0];
  const float oscale = (z==0) ? 0.18033688011112042f : 1.0f;  // 0.125*log2(e) for Q
  #pragma unroll
  for (int ni = 0; ni < 4; ni++){
    const int n = n0 + wn*64 + ni*16 + l15;
    const float biasv = bias[n] + emb[index*HH + n];
    const int h = n >> 6, d = n & 63;
    #pragma unroll
    for (int mi = 0; mi < 4; mi++){
      #pragma unroll
      for (int r = 0; r < 4; r++){
        const int g  = m0 + wm*64 + mi*16 + quad*4 + r;
        const int b_ = g >> 11;
        const int s_ = g & (SS - 1);
        const int bh = b_*NHH + h;
        const unsigned short val = f2bf((acc[mi][ni][r] + biasv) * oscale);
        if (z == 2)      wsq[VT_OFF + (size_t)(bh*HDD + d)*SS + s_] = val;
        else if (z == 0) wsq[Q_OFF  + (size_t)(bh*SS + s_)*HDD + d] = val;
        else             wsq[K_OFF  + (size_t)(bh*SS + s_)*HDD + d] = val;
      }
    }
  }
}

// ---------------- kernel 3: flash attention, kt split across waves ----------------
// Block = 32 q rows (qg=2, low register footprint -> 4 waves/SIMD).
// Wave w owns kt in [w*512,(w+1)*512), 16 chunks of 32; fixed-max softmax so
// per-wave partial l/O merge by plain addition at the end.
// XCD swizzle: all 64 q-blocks of a (b,h) land on one XCD (assuming xcd = bx%8)
// so K/V (512 KB) stays in that XCD's 4 MB L2.
#define ST_P 40   // plds row stride (shorts): 80B, 16B-aligned
#define ST_O 68   // obuf row stride (dwords): 272B, 16B-aligned
__global__ __launch_bounds__(256, 4) void attn_mfma(
    const unsigned short* __restrict__ ws16,
    const float* __restrict__ mask, float* __restrict__ out){
  __shared__ __align__(16) unsigned char shraw[4*32*ST_P*2];  // 10240 B, dual-purpose
  __shared__ float mlds[SS];                                  // mask row * log2(e)

  unsigned short* plds = (unsigned short*)shraw;      // [4][32*ST_P] during main loop
  float (*obuf)[ST_O]  = (float(*)[ST_O])shraw;       // [32][ST_O] during merge (8704 B)
  float* lpart         = (float*)(shraw + 8704);      // [4][32] during merge (512 B)

  const int tid  = threadIdx.x;
  const int wave = tid >> 6;
  const int lane = tid & 63;
  const int quad = lane >> 4;
  const int l15  = lane & 15;

  // XCD-aware swizzle: bh = (bx&7) + 8*((bx>>3)&7), qb = bx>>6
  const int bx  = blockIdx.x;
  const int bh  = (bx & 7) + 8*((bx >> 3) & 7);
  const int qb  = bx >> 6;                // 0..63
  const int b   = bh >> 4, h = bh & 15;
  const int q0  = qb*32;
  const float LOG2E = 1.4426950408889634f;

  // stage mask row, pre-scaled by log2(e)
  {
    const float4* mp = (const float4*)(mask + b*SS);
    float4 a = mp[tid*2 + 0], c = mp[tid*2 + 1];
    a.x*=LOG2E; a.y*=LOG2E; a.z*=LOG2E; a.w*=LOG2E;
    c.x*=LOG2E; c.y*=LOG2E; c.z*=LOG2E; c.w*=LOG2E;
    *(float4*)&mlds[tid*8 + 0] = a;
    *(float4*)&mlds[tid*8 + 4] = c;
  }
  __syncthreads();

  const unsigned short* Qg = ws16 + Q_OFF  + (size_t)bh*SS*HDD;
  const unsigned short* Kg = ws16 + K_OFF  + (size_t)bh*SS*HDD;
  const unsigned short* Vg = ws16 + VT_OFF + (size_t)bh*HDD*SS;

  // Q fragments for 32 q rows (B-operand: n=q=qg*16+l15, k=d=quad*8+j), resident
  bf16x8 aq[2][2];
  #pragma unroll
  for (int qg = 0; qg < 2; qg++){
    aq[qg][0] = *(const bf16x8*)(Qg + (size_t)(q0 + qg*16 + l15)*HDD + quad*8);
    aq[qg][1] = *(const bf16x8*)(Qg + (size_t)(q0 + qg*16 + l15)*HDD + 32 + quad*8);
  }

  f32x4 O[4][2] = {};          // O^T partial: [dg][qg], elem (d=dg*16+quad*4+r, q=qg*16+l15)
  float lacc[2] = {0.f, 0.f};
  unsigned short* pw = &plds[wave*32*ST_P];

  #pragma unroll 1
  for (int ch = 0; ch < 16; ch++){
    const int ktb = wave*512 + ch*32;

    // K fragments: A-operand (m=kt=fi*16+l15, k=d), direct from global (L2-resident)
    bf16x8 ka[2][2];
    #pragma unroll
    for (int fi = 0; fi < 2; fi++){
      ka[fi][0] = *(const bf16x8*)&Kg[(size_t)(ktb + fi*16 + l15)*HDD + quad*8];
      ka[fi][1] = *(const bf16x8*)&Kg[(size_t)(ktb + fi*16 + l15)*HDD + 32 + quad*8];
    }
    // V^T fragments: A-operand (m=d=dg*16+l15, k=kt=quad*8+j), direct from global
    bf16x8 va[4];
    #pragma unroll
    for (int dg = 0; dg < 4; dg++)
      va[dg] = *(const bf16x8*)&Vg[(size_t)(dg*16 + l15)*SS + ktb + quad*8];

    // ---- S^T = K·Q^T with C init = mask -> p = exp2(st) -> P^T to LDS ----
    #pragma unroll
    for (int fi = 0; fi < 2; fi++){
      const f32x4 mv = *(const f32x4*)&mlds[ktb + fi*16 + quad*4];
      #pragma unroll
      for (int qg = 0; qg < 2; qg++){
        f32x4 st = mv;   // accumulator pre-loaded with log2e-scaled mask
        st = __builtin_amdgcn_mfma_f32_16x16x32_bf16(ka[fi][0], aq[qg][0], st, 0,0,0);
        st = __builtin_amdgcn_mfma_f32_16x16x32_bf16(ka[fi][1], aq[qg][1], st, 0,0,0);
        f32x4 p;
        #pragma unroll
        for (int r = 0; r < 4; r++) p[r] = __builtin_amdgcn_exp2f(st[r]);
        lacc[qg] += (p[0] + p[1]) + (p[2] + p[3]);
        uint2 w; w.x = pk2bf(p[0], p[1]); w.y = pk2bf(p[2], p[3]);
        *(uint2*)&pw[(qg*16 + l15)*ST_P + fi*16 + quad*4] = w;
      }
    }

    // ---- O^T += V^T · P^T (intra-wave LDS round-trip, wave-ordered, no barrier) ----
    #pragma unroll
    for (int qg = 0; qg < 2; qg++){
      bf16x8 bp = *(const bf16x8*)&pw[(qg*16 + l15)*ST_P + quad*8];
      #pragma unroll
      for (int dg = 0; dg < 4; dg++)
        O[dg][qg] = __builtin_amdgcn_mfma_f32_16x16x32_bf16(va[dg], bp, O[dg][qg], 0,0,0);
    }
  }

  // ---- all waves done with plds; switch region to obuf/lpart ----
  __syncthreads();

  // l partials: reduce across quads (shfl), store per wave
  #pragma unroll
  for (int qg = 0; qg < 2; qg++){
    float lq = lacc[qg];
    lq += __shfl_xor(lq, 16);
    lq += __shfl_xor(lq, 32);
    if (quad == 0) lpart[wave*32 + qg*16 + l15] = lq;
  }

  // phased O merge into obuf (float4, conflict-free)
  #pragma unroll
  for (int w = 0; w < 4; w++){
    if (wave == w){
      #pragma unroll
      for (int qg = 0; qg < 2; qg++){
        #pragma unroll
        for (int dg = 0; dg < 4; dg++){
          float* dst = &obuf[qg*16 + l15][dg*16 + quad*4];
          f32x4 v = O[dg][qg];
          if (w != 0){ f32x4 o = *(f32x4*)dst; v[0]+=o[0]; v[1]+=o[1]; v[2]+=o[2]; v[3]+=o[3]; }
          *(f32x4*)dst = v;
        }
      }
    }
    __syncthreads();
  }

  // epilogue: scale by 1/l, write ctx [B,S,H] fp32 (8 floats per thread, coalesced)
  const int q  = tid >> 3;              // 0..31
  const int d0 = (tid & 7)*8;
  const float ls = lpart[0*32 + q] + lpart[1*32 + q] + lpart[2*32 + q] + lpart[3*32 + q];
  const float inv = 1.0f / ls;
  float* op = out + ((size_t)b*SS + q0 + q)*HH + h*HDD + d0;
  #pragma unroll
  for (int i = 0; i < 2; i++){
    f32x4 v = *(f32x4*)&obuf[q][d0 + i*4];
    float4 o; o.x = v[0]*inv; o.y = v[1]*inv; o.z = v[2]*inv; o.w = v[3]*inv;
    *(float4*)&op[i*4] = o;
  }
}

extern "C" void kernel_launch(void* const* d_in, const int* in_sizes, int n_in,
                              void* d_out, int out_size, void* d_ws, size_t ws_size,
                              hipStream_t stream){
  const float* hs   = (const float*)d_in[0];
  const float* mask = (const float*)d_in[1];
  const float* Wq   = (const float*)d_in[2];
  const float* bq   = (const float*)d_in[3];
  const float* Wk   = (const float*)d_in[4];
  const float* bk   = (const float*)d_in[5];
  const float* Wv   = (const float*)d_in[6];
  const float* bv   = (const float*)d_in[7];
  const float* qe   = (const float*)d_in[8];
  const float* ke   = (const float*)d_in[9];
  const float* ve   = (const float*)d_in[10];
  const int*   idx  = (const int*)d_in[11];
  unsigned short* ws16 = (unsigned short*)d_ws;
  float* out = (float*)d_out;

  convert_x<<<M_TOT*HH/4/256, 256, 0, stream>>>(hs, ws16 + XB_OFF);
  dim3 gt(HH/64, HH/64, 3);
  convert_wt<<<gt, 256, 0, stream>>>(Wq, Wk, Wv, ws16 + WT_OFF);

  dim3 g2(M_TOT/128, HH/128, 3);
  qkv_gemm<<<g2, 256, 0, stream>>>(ws16, ws16, bq, bk, bv, qe, ke, ve, idx);

  attn_mfma<<<BB*NHH*SS/32, 256, 0, stream>>>(ws16, mask, out);
}

// Round 8
// 360.274 us; speedup vs baseline: 1.2120x; 1.2120x over previous
//
#include <hip/hip_runtime.h>
#include <hip/hip_bf16.h>
#include <stdint.h>

#define BB 4
#define SS 2048
#define HH 1024
#define NHH 16
#define HDD 64
#define M_TOT (BB*SS)          // 8192

// workspace layout (ushort/bf16 element offsets)
#define XB_OFF 0                              // hidden bf16 [8192][1024]
#define WT_OFF (M_TOT*HH)                     // Wq^T,Wk^T,Wv^T bf16 [3][N=1024][K=1024]
#define Q_OFF  (WT_OFF + 3*HH*HH)             // Q  [B][NH][S][HD]  (pre-scaled by 0.125*log2e!)
#define K_OFF  (Q_OFF + BB*NHH*SS*HDD)        // K  [B][NH][S][HD]
#define VT_OFF (K_OFF + BB*NHH*SS*HDD)        // Vt [B][NH][HD][S]  (transposed)

typedef short bf16x8 __attribute__((ext_vector_type(8)));
typedef float f32x4  __attribute__((ext_vector_type(4)));

__device__ inline unsigned short f2bf(float f){
  unsigned u = __float_as_uint(f);
  u += 0x7fffu + ((u >> 16) & 1u);   // RNE
  return (unsigned short)(u >> 16);
}
__device__ inline unsigned pk2bf(float lo, float hi){
  float2 t; t.x = lo; t.y = hi;
  __hip_bfloat162 h = __float22bfloat162_rn(t);
  return *(unsigned*)&h;
}

// async global->LDS, 16B per lane
__device__ __forceinline__ void ld_g2l_16(const unsigned short* g, unsigned short* l){
  __builtin_amdgcn_global_load_lds(
      (const __attribute__((address_space(1))) void*)g,
      (__attribute__((address_space(3))) void*)l, 16, 0, 0);
}

// ---------------- kernel 1a: X fp32 -> bf16 ----------------
__global__ void convert_x(const float* __restrict__ hs, unsigned short* __restrict__ xb){
  const int i = blockIdx.x*blockDim.x + threadIdx.x;
  float4 v = ((const float4*)hs)[i];
  ushort4 o;
  o.x = f2bf(v.x); o.y = f2bf(v.y); o.z = f2bf(v.z); o.w = f2bf(v.w);
  ((ushort4*)xb)[i] = o;
}

// ---------------- kernel 1b: W [K][N] fp32 -> WT [N][K] bf16 ----------------
__global__ void convert_wt(const float* __restrict__ wq, const float* __restrict__ wk,
                           const float* __restrict__ wv, unsigned short* __restrict__ wt){
  __shared__ unsigned short t[64][65];
  const int z = blockIdx.z;
  const float* W = (z==0) ? wq : ((z==1) ? wk : wv);
  unsigned short* WT = wt + z*HH*HH;
  const int kb = blockIdx.x*64, nb = blockIdx.y*64;
  const int tid = threadIdx.x;
  #pragma unroll
  for (int i = 0; i < 16; i++){
    const int idx = i*256 + tid;
    const int r = idx >> 6, c = idx & 63;
    t[r][c] = f2bf(W[(kb + r)*HH + nb + c]);
  }
  __syncthreads();
  #pragma unroll
  for (int i = 0; i < 16; i++){
    const int idx = i*256 + tid;
    const int n = idx >> 6, k = idx & 63;
    WT[(nb + n)*HH + kb + k] = t[k][n];
  }
}

// ---------------- kernel 2: QKV projection GEMM (m97 structure) ----------------
// z==0 (Q) output is pre-scaled by 0.125*log2e so attention needs no per-score fma.
__global__ __launch_bounds__(256) void qkv_gemm(
    const unsigned short* __restrict__ ws16, unsigned short* __restrict__ wsq,
    const float* __restrict__ bq, const float* __restrict__ bk, const float* __restrict__ bv,
    const float* __restrict__ qe, const float* __restrict__ ke, const float* __restrict__ ve,
    const int* __restrict__ idxp){
  __shared__ unsigned short al[128*32];
  __shared__ unsigned short bl[128*32];

  const unsigned short* Xb = ws16 + XB_OFF;
  const int z = blockIdx.z;
  const unsigned short* Wt = ws16 + WT_OFF + z*HH*HH;
  const float* bias = (z==0) ? bq : ((z==1) ? bk : bv);
  const float* emb  = (z==0) ? qe : ((z==1) ? ke : ve);

  const int tid  = threadIdx.x;
  const int wv   = tid >> 6;
  const int ln   = tid & 63;
  const int quad = ln >> 4;
  const int l15  = ln & 15;
  const int m0 = blockIdx.x * 128;
  const int n0 = blockIdx.y * 128;
  const int wm = wv & 1, wn = wv >> 1;

  const int sr0 = wv*32 + (ln >> 2);
  const int sr1 = sr0 + 16;
  const int sk  = (ln & 3)*8;
  const unsigned short* ga0 = &Xb[(size_t)(m0 + sr0)*HH + sk];
  const unsigned short* ga1 = &Xb[(size_t)(m0 + sr1)*HH + sk];
  const unsigned short* gb0 = &Wt[(size_t)(n0 + sr0)*HH + sk];
  const unsigned short* gb1 = &Wt[(size_t)(n0 + sr1)*HH + sk];
  unsigned short* alb0 = &al[wv*1024];
  unsigned short* alb1 = &al[wv*1024 + 512];
  unsigned short* blb0 = &bl[wv*1024];
  unsigned short* blb1 = &bl[wv*1024 + 512];

  f32x4 acc[4][4] = {};

  for (int k0 = 0; k0 < HH; k0 += 32){
    __syncthreads();
    ld_g2l_16(ga0 + k0, alb0);
    ld_g2l_16(ga1 + k0, alb1);
    ld_g2l_16(gb0 + k0, blb0);
    ld_g2l_16(gb1 + k0, blb1);
    __syncthreads();

    bf16x8 af[4], bf[4];
    #pragma unroll
    for (int i = 0; i < 4; i++){
      af[i] = *(const bf16x8*)&al[(wm*64 + i*16 + l15)*32 + quad*8];
      bf[i] = *(const bf16x8*)&bl[(wn*64 + i*16 + l15)*32 + quad*8];
    }
    #pragma unroll
    for (int mi = 0; mi < 4; mi++)
      #pragma unroll
      for (int ni = 0; ni < 4; ni++)
        acc[mi][ni] = __builtin_amdgcn_mfma_f32_16x16x32_bf16(af[mi], bf[ni], acc[mi][ni], 0, 0, 0);
  }

  const int index = idxp[0];
  const float oscale = (z==0) ? 0.18033688011112042f : 1.0f;  // 0.125*log2(e) for Q
  #pragma unroll
  for (int ni = 0; ni < 4; ni++){
    const int n = n0 + wn*64 + ni*16 + l15;
    const float biasv = bias[n] + emb[index*HH + n];
    const int h = n >> 6, d = n & 63;
    #pragma unroll
    for (int mi = 0; mi < 4; mi++){
      #pragma unroll
      for (int r = 0; r < 4; r++){
        const int g  = m0 + wm*64 + mi*16 + quad*4 + r;
        const int b_ = g >> 11;
        const int s_ = g & (SS - 1);
        const int bh = b_*NHH + h;
        const unsigned short val = f2bf((acc[mi][ni][r] + biasv) * oscale);
        if (z == 2)      wsq[VT_OFF + (size_t)(bh*HDD + d)*SS + s_] = val;
        else if (z == 0) wsq[Q_OFF  + (size_t)(bh*SS + s_)*HDD + d] = val;
        else             wsq[K_OFF  + (size_t)(bh*SS + s_)*HDD + d] = val;
      }
    }
  }
}

// ---------------- kernel 3: flash attention, kt split across waves ----------------
// Block = 64 q rows (qg=4), 4 waves each owning kt in [w*512,(w+1)*512), 16 chunks
// of 32. Fixed-max softmax -> per-wave partial l/O merged by addition at the end.
// Modulo-2 software pipeline: chunk ch+1's 8 K/V fragment loads issue before chunk
// ch's compute (S-MFMA -> exp2 -> P LDS round-trip -> PV-MFMA) -> L2 latency hidden
// within the wave (R6 lesson: per-wave ILP > occupancy for this loop).
// XCD swizzle: all 32 q-blocks of a (b,h) land on one XCD (xcd = bx%8 assumption).
#define ST_P 40   // plds row stride (shorts): 80B, 16B-aligned
#define ST_O 68   // obuf row stride (dwords): 272B, 16B-aligned
__global__ __launch_bounds__(256) void attn_mfma(
    const unsigned short* __restrict__ ws16,
    const float* __restrict__ mask, float* __restrict__ out){
  __shared__ __align__(16) unsigned char shraw[4*64*ST_P*2];  // 20480 B, dual-purpose
  __shared__ float mlds[SS];                                  // mask row * log2(e)

  unsigned short* plds = (unsigned short*)shraw;      // [4][64*ST_P] during main loop
  float (*obuf)[ST_O]  = (float(*)[ST_O])shraw;       // [64][ST_O] during merge (17408 B)
  float* lpart         = (float*)(shraw + 17408);     // [4][64] during merge (1024 B)

  const int tid  = threadIdx.x;
  const int wave = tid >> 6;
  const int lane = tid & 63;
  const int quad = lane >> 4;
  const int l15  = lane & 15;

  // XCD-aware swizzle: bh = (bx&7) + 8*((bx>>3)&7), qb = bx>>6  (grid 2048 = 64bh x 32qb)
  const int bx  = blockIdx.x;
  const int bh  = (bx & 7) + 8*((bx >> 3) & 7);
  const int qb  = bx >> 6;
  const int b   = bh >> 4, h = bh & 15;
  const int q0  = qb*64;
  const float LOG2E = 1.4426950408889634f;

  // stage mask row, pre-scaled by log2(e)
  {
    const float4* mp = (const float4*)(mask + b*SS);
    float4 a = mp[tid*2 + 0], c = mp[tid*2 + 1];
    a.x*=LOG2E; a.y*=LOG2E; a.z*=LOG2E; a.w*=LOG2E;
    c.x*=LOG2E; c.y*=LOG2E; c.z*=LOG2E; c.w*=LOG2E;
    *(float4*)&mlds[tid*8 + 0] = a;
    *(float4*)&mlds[tid*8 + 4] = c;
  }
  __syncthreads();

  const unsigned short* Qg = ws16 + Q_OFF  + (size_t)bh*SS*HDD;
  const unsigned short* Kg = ws16 + K_OFF  + (size_t)bh*SS*HDD;
  const unsigned short* Vg = ws16 + VT_OFF + (size_t)bh*HDD*SS;

  // per-wave K/V base pointers (chunk stride added via immediate-style offsets)
  const unsigned short* kp = Kg + (size_t)(wave*512 + l15)*HDD + quad*8;
  const unsigned short* vp = Vg + (size_t)l15*SS + wave*512 + quad*8;

  // Q fragments for all 64 q rows (B-operand: n=q=qg*16+l15, k=d=quad*8+j), resident
  bf16x8 aq[4][2];
  #pragma unroll
  for (int qg = 0; qg < 4; qg++){
    aq[qg][0] = *(const bf16x8*)(Qg + (size_t)(q0 + qg*16 + l15)*HDD + quad*8);
    aq[qg][1] = *(const bf16x8*)(Qg + (size_t)(q0 + qg*16 + l15)*HDD + 32 + quad*8);
  }

  f32x4 O[4][4] = {};          // O^T partial: [dg][qg], elem (d=dg*16+quad*4+r, q=qg*16+l15)
  float lacc[4] = {0.f,0.f,0.f,0.f};
  unsigned short* pw = &plds[wave*64*ST_P];
  const int mbase = wave*512;

  // fragment load: chunk ch covers kt = wave*512 + ch*32 .. +31
#define LOADF(KA, VA, CH) do {                                                  \
    const unsigned short* kc = kp + (size_t)(CH)*32*HDD;                        \
    KA[0][0] = *(const bf16x8*)(kc);                                            \
    KA[0][1] = *(const bf16x8*)(kc + 32);                                       \
    KA[1][0] = *(const bf16x8*)(kc + 16*HDD);                                   \
    KA[1][1] = *(const bf16x8*)(kc + 16*HDD + 32);                              \
    const unsigned short* vc = vp + (CH)*32;                                    \
    VA[0] = *(const bf16x8*)(vc);                                               \
    VA[1] = *(const bf16x8*)(vc + 16*SS);                                       \
    VA[2] = *(const bf16x8*)(vc + 32*SS);                                       \
    VA[3] = *(const bf16x8*)(vc + 48*SS);                                       \
  } while(0)

  auto compute = [&](bf16x8 (&ka)[2][2], bf16x8 (&va)[4], int ch){
    const int mo = mbase + ch*32;
    #pragma unroll
    for (int fi = 0; fi < 2; fi++){
      const f32x4 mv = *(const f32x4*)&mlds[mo + fi*16 + quad*4];
      #pragma unroll
      for (int qg = 0; qg < 4; qg++){
        f32x4 st = mv;   // accumulator pre-loaded with log2e-scaled mask
        st = __builtin_amdgcn_mfma_f32_16x16x32_bf16(ka[fi][0], aq[qg][0], st, 0,0,0);
        st = __builtin_amdgcn_mfma_f32_16x16x32_bf16(ka[fi][1], aq[qg][1], st, 0,0,0);
        f32x4 p;
        #pragma unroll
        for (int r = 0; r < 4; r++) p[r] = __builtin_amdgcn_exp2f(st[r]);
        lacc[qg] += (p[0] + p[1]) + (p[2] + p[3]);
        uint2 w; w.x = pk2bf(p[0], p[1]); w.y = pk2bf(p[2], p[3]);
        *(uint2*)&pw[(qg*16 + l15)*ST_P + fi*16 + quad*4] = w;
      }
    }
    #pragma unroll
    for (int qg = 0; qg < 4; qg++){
      bf16x8 bp = *(const bf16x8*)&pw[(qg*16 + l15)*ST_P + quad*8];
      #pragma unroll
      for (int dg = 0; dg < 4; dg++)
        O[dg][qg] = __builtin_amdgcn_mfma_f32_16x16x32_bf16(va[dg], bp, O[dg][qg], 0,0,0);
    }
  };

  bf16x8 kaA[2][2], vaA[4], kaB[2][2], vaB[4];
  LOADF(kaA, vaA, 0);
  #pragma unroll 1
  for (int ch = 0; ch < 16; ch += 2){
    LOADF(kaB, vaB, ch + 1);          // prefetch odd chunk
    compute(kaA, vaA, ch);
    if (ch + 2 < 16) LOADF(kaA, vaA, ch + 2);   // prefetch next even chunk
    compute(kaB, vaB, ch + 1);
  }
#undef LOADF

  // ---- all waves done with plds; switch region to obuf/lpart ----
  __syncthreads();

  // l partials: reduce across quads (shfl), store per wave
  #pragma unroll
  for (int qg = 0; qg < 4; qg++){
    float lq = lacc[qg];
    lq += __shfl_xor(lq, 16);
    lq += __shfl_xor(lq, 32);
    if (quad == 0) lpart[wave*64 + qg*16 + l15] = lq;
  }

  // phased O merge into obuf (float4, conflict-free)
  #pragma unroll
  for (int w = 0; w < 4; w++){
    if (wave == w){
      #pragma unroll
      for (int qg = 0; qg < 4; qg++){
        #pragma unroll
        for (int dg = 0; dg < 4; dg++){
          float* dst = &obuf[qg*16 + l15][dg*16 + quad*4];
          f32x4 v = O[dg][qg];
          if (w != 0){ f32x4 o = *(f32x4*)dst; v[0]+=o[0]; v[1]+=o[1]; v[2]+=o[2]; v[3]+=o[3]; }
          *(f32x4*)dst = v;
        }
      }
    }
    __syncthreads();
  }

  // epilogue: scale by 1/l, write ctx [B,S,H] fp32
  const int q  = tid >> 2;
  const int c4 = tid & 3;
  const float ls = lpart[0*64 + q] + lpart[1*64 + q] + lpart[2*64 + q] + lpart[3*64 + q];
  const float inv = 1.0f / ls;
  float* op = out + ((size_t)b*SS + q0 + q)*HH + h*HDD + c4*16;
  #pragma unroll
  for (int i = 0; i < 4; i++){
    f32x4 v = *(f32x4*)&obuf[q][c4*16 + i*4];
    float4 o; o.x = v[0]*inv; o.y = v[1]*inv; o.z = v[2]*inv; o.w = v[3]*inv;
    *(float4*)&op[i*4] = o;
  }
}

extern "C" void kernel_launch(void* const* d_in, const int* in_sizes, int n_in,
                              void* d_out, int out_size, void* d_ws, size_t ws_size,
                              hipStream_t stream){
  const float* hs   = (const float*)d_in[0];
  const float* mask = (const float*)d_in[1];
  const float* Wq   = (const float*)d_in[2];
  const float* bq   = (const float*)d_in[3];
  const float* Wk   = (const float*)d_in[4];
  const float* bk   = (const float*)d_in[5];
  const float* Wv   = (const float*)d_in[6];
  const float* bv   = (const float*)d_in[7];
  const float* qe   = (const float*)d_in[8];
  const float* ke   = (const float*)d_in[9];
  const float* ve   = (const float*)d_in[10];
  const int*   idx  = (const int*)d_in[11];
  unsigned short* ws16 = (unsigned short*)d_ws;
  float* out = (float*)d_out;

  convert_x<<<M_TOT*HH/4/256, 256, 0, stream>>>(hs, ws16 + XB_OFF);
  dim3 gt(HH/64, HH/64, 3);
  convert_wt<<<gt, 256, 0, stream>>>(Wq, Wk, Wv, ws16 + WT_OFF);

  dim3 g2(M_TOT/128, HH/128, 3);
  qkv_gemm<<<g2, 256, 0, stream>>>(ws16, ws16, bq, bk, bv, qe, ke, ve, idx);

  attn_mfma<<<BB*NHH*SS/64, 256, 0, stream>>>(ws16, mask, out);
}